// Round 1
// baseline (5818.898 us; speedup 1.0000x reference)
//
#include <hip/hip_runtime.h>
#include <hip/hip_fp16.h>

// LSTM: VOCAB=100, INPUT=512, HIDDEN=1024, BATCH=64, SEQ=512
// out = latent[64][512][1024] f32, then h_f[64][1024], c_f[64][1024]

typedef _Float16 f16x8 __attribute__((ext_vector_type(8)));
typedef float    f32x4 __attribute__((ext_vector_type(4)));

#define VOCABN 100

// ---------------- K0: zx_table[v][g][n] = emb[v] . Wg[n, 0:512] + b_g[n] ----------------
__global__ void k0_zxtable(const float* __restrict__ emb,
                           const float* __restrict__ Wf, const float* __restrict__ bf,
                           const float* __restrict__ Wi, const float* __restrict__ bi,
                           const float* __restrict__ Wo, const float* __restrict__ bo,
                           const float* __restrict__ Wg, const float* __restrict__ bg_,
                           float* __restrict__ zx) {
  const int bid = blockIdx.x;            // 256 blocks: (gate, 16-unit chunk)
  const int g = bid >> 6, chunk = bid & 63;
  const float* W = (g==0)?Wf:(g==1)?Wi:(g==2)?Wo:Wg;
  const float* B = (g==0)?bf:(g==1)?bi:(g==2)?bo:bg_;
  __shared__ float Wl[16][516];          // 16 rows x 512 (pad to 516)
  const int tid = threadIdx.x;
  for (int i = tid; i < 2048; i += 256) {        // 2048 float4 = 16x512 f32
    int r = i >> 7, c4 = i & 127;
    float4 v = *(const float4*)&W[(size_t)(chunk*16 + r)*1536 + c4*4];
    Wl[r][c4*4+0]=v.x; Wl[r][c4*4+1]=v.y; Wl[r][c4*4+2]=v.z; Wl[r][c4*4+3]=v.w;
  }
  __syncthreads();
  const int u = tid & 15, vi = tid >> 4;
  for (int v0 = 0; v0 < VOCABN; v0 += 16) {
    int v = v0 + vi;
    if (v < VOCABN) {
      const float* er = emb + (size_t)v*512;
      float acc = 0.f;
      #pragma unroll 8
      for (int k = 0; k < 512; k++) acc += er[k]*Wl[u][k];
      zx[(size_t)v*4096 + g*1024 + chunk*16 + u] = acc + B[chunk*16 + u];
    }
  }
}

// ---------------- K1: Whh fp16 conversion + h0 -> hbuf[1] fp16 ----------------
__global__ void k1_prep(const float* __restrict__ Wf, const float* __restrict__ Wi,
                        const float* __restrict__ Wo, const float* __restrict__ Wg,
                        const float* __restrict__ h0,
                        _Float16* __restrict__ Whh, _Float16* __restrict__ hbuf) {
  const int bid = blockIdx.x, tid = threadIdx.x;
  if (bid < 1024) {
    // Whh[g][n][k] = (f16) W_g[n][512+k]; 4*1024*1024 halves = 1,048,576 float4 reads
    #pragma unroll
    for (int i = 0; i < 4; i++) {
      int F = bid*1024 + i*256 + tid;          // float4 index
      int g = F >> 18;
      int rem = F & ((1<<18)-1);
      int n = rem >> 8, k4 = rem & 255;
      const float* W = (g==0)?Wf:(g==1)?Wi:(g==2)?Wo:Wg;
      float4 v = *(const float4*)&W[(size_t)n*1536 + 512 + k4*4];
      _Float16 h4[4] = {(_Float16)v.x,(_Float16)v.y,(_Float16)v.z,(_Float16)v.w};
      *(unsigned long long*)&Whh[((size_t)g<<20) + (n<<10) + (k4<<2)] =
          *(unsigned long long*)h4;
    }
  } else {
    int j = bid - 1024;                         // 64 blocks: h0 [64][1024] -> f16 buf 1
    int base = j*1024 + tid*4;
    float4 v = *(const float4*)&h0[base];
    _Float16 h4[4] = {(_Float16)v.x,(_Float16)v.y,(_Float16)v.z,(_Float16)v.w};
    *(unsigned long long*)&hbuf[65536 + base] = *(unsigned long long*)h4;
  }
}

// ---------------- Main persistent LSTM kernel ----------------
// grid 256 = 4 batch-groups x 64 j-slices; block 256 thr = 4 waves (one per gate)
__global__ __launch_bounds__(256, 1) void lstm_main(
    const int* __restrict__ X, const float* __restrict__ c0,
    const float* __restrict__ zx, const _Float16* __restrict__ Whh,
    _Float16* __restrict__ hbuf, int* __restrict__ flags,
    float* __restrict__ out)
{
  const int bid  = blockIdx.x;
  const int bg   = bid >> 6;            // batch group (16 batches)
  const int js   = bid & 63;            // 16-unit slice
  const int tid  = threadIdx.x;
  const int wave = tid >> 6;            // gate id
  const int lane = tid & 63;
  const int lm   = lane & 15, lh = lane >> 4;

  __shared__ alignas(16) _Float16 hs[16][1032];   // 16 batches x 1024 (padded)
  __shared__ float zsh[16][68];                   // z exchange [b][4*16 gates]

  // Preload this wave's B fragments: W_gate rows n=16js..16js+15, K=1024 (32 k-tiles)
  f16x8 bw[32];
  {
    const _Float16* wrow = Whh + ((size_t)wave<<20) + ((size_t)(js*16 + lm)<<10) + (lh<<3);
    #pragma unroll
    for (int kk = 0; kk < 32; kk++) bw[kk] = *(const f16x8*)(wrow + kk*32);
  }

  const int bl = tid >> 4, u = tid & 15;          // this thread's (batch,unit) in phase4
  const int brow = bg*16 + bl;
  const int ucol = js*16 + u;
  float c = c0[(size_t)brow*1024 + ucol];
  const int* Xrow = X + (size_t)brow*512;
  float* latp = out + (size_t)brow*512*1024 + ucol;
  int* gflags = flags + bg*64;

  for (int t = 0; t < 512; t++) {
    // ---- stage h_prev (16x1024 f16) into LDS ----
    const _Float16* src = hbuf + (((t&1)^1)<<16) + (bg<<14);
    #pragma unroll
    for (int i = 0; i < 8; i++) {
      int idx = i*256 + tid;                      // 2048 x 16B
      int r = idx >> 7, cc = idx & 127;
      *(f16x8*)&hs[r][cc*8] = *(const f16x8*)&src[(r<<10) + (cc<<3)];
    }
    __syncthreads();

    // ---- MFMA: z_gate[16b x 16u] = h[16x1024] . Wg_slice^T ----
    f32x4 a0={0,0,0,0}, a1={0,0,0,0}, a2={0,0,0,0}, a3={0,0,0,0};
    const _Float16* hrow = &hs[lm][lh<<3];
    #pragma unroll
    for (int kk = 0; kk < 32; kk += 4) {
      f16x8 x0 = *(const f16x8*)(hrow + (kk+0)*32);
      f16x8 x1 = *(const f16x8*)(hrow + (kk+1)*32);
      f16x8 x2 = *(const f16x8*)(hrow + (kk+2)*32);
      f16x8 x3 = *(const f16x8*)(hrow + (kk+3)*32);
      a0 = __builtin_amdgcn_mfma_f32_16x16x32_f16(x0, bw[kk+0], a0, 0, 0, 0);
      a1 = __builtin_amdgcn_mfma_f32_16x16x32_f16(x1, bw[kk+1], a1, 0, 0, 0);
      a2 = __builtin_amdgcn_mfma_f32_16x16x32_f16(x2, bw[kk+2], a2, 0, 0, 0);
      a3 = __builtin_amdgcn_mfma_f32_16x16x32_f16(x3, bw[kk+3], a3, 0, 0, 0);
    }
    f32x4 z4 = (a0 + a1) + (a2 + a3);
    #pragma unroll
    for (int r = 0; r < 4; r++)                    // D: row=(lane>>4)*4+r, col=lane&15
      zsh[(lh<<2) + r][wave*16 + lm] = z4[r];
    __syncthreads();

    // ---- gates + state update (thread = one (batch, unit)) ----
    float zf = zsh[bl][u],      zi = zsh[bl][16+u];
    float zo = zsh[bl][32+u],   zg = zsh[bl][48+u];
    int xv = Xrow[t];
    const float* zxp = zx + (size_t)xv*4096 + ucol;
    zf += zxp[0]; zi += zxp[1024]; zo += zxp[2048]; zg += zxp[3072];
    float fg = 1.f/(1.f + expf(-zf));
    float ig = 1.f/(1.f + expf(-zi));
    float og = 1.f/(1.f + expf(-zo));
    float gg = tanhf(zg);
    c = fg*c + ig*gg;
    float h = og*tanhf(c);

    __builtin_nontemporal_store(h, latp + (size_t)t*1024);
    hbuf[((t&1)<<16) + (brow<<10) + ucol] = (_Float16)h;
    if (t == 511) {
      out[33554432 + (brow<<10) + ucol] = h;   // h_f
      out[33619968 + (brow<<10) + ucol] = c;   // c_f
    }

    // ---- group barrier (64 blocks sharing this batch group) ----
    __syncthreads();                      // drains vmcnt before s_barrier
    if (wave == 0) {
      if (lane == 0)
        __hip_atomic_store(&gflags[js], t+1, __ATOMIC_RELEASE, __HIP_MEMORY_SCOPE_AGENT);
      int v;
      do {
        v = __hip_atomic_load(&gflags[lane], __ATOMIC_RELAXED, __HIP_MEMORY_SCOPE_AGENT);
      } while (v <= t);
      __builtin_amdgcn_fence(__ATOMIC_ACQUIRE, "agent");
    }
    __syncthreads();
  }
}

extern "C" void kernel_launch(void* const* d_in, const int* in_sizes, int n_in,
                              void* d_out, int out_size, void* d_ws, size_t ws_size,
                              hipStream_t stream) {
  const int*   X   = (const int*)  d_in[0];
  const float* h0  = (const float*)d_in[1];
  const float* c0  = (const float*)d_in[2];
  const float* emb = (const float*)d_in[3];
  const float* Wf  = (const float*)d_in[4];  const float* bf = (const float*)d_in[5];
  const float* Wi  = (const float*)d_in[6];  const float* bi = (const float*)d_in[7];
  const float* Wo  = (const float*)d_in[8];  const float* bo = (const float*)d_in[9];
  const float* Wg  = (const float*)d_in[10]; const float* bg = (const float*)d_in[11];
  float* out = (float*)d_out;

  char* ws = (char*)d_ws;
  float*    zx    = (float*)   ws;                         // 100*4096*4   = 1,638,400 B
  _Float16* Whh   = (_Float16*)(ws + 1638400);             // 4*1024*1024*2 = 8,388,608 B
  _Float16* hbuf  = (_Float16*)(ws + 1638400 + 8388608);   // 2*64*1024*2  =   262,144 B
  int*      flags = (int*)     (ws + 1638400 + 8388608 + 262144); // 256*4 = 1024 B

  hipMemsetAsync(flags, 0, 256*sizeof(int), stream);
  k0_zxtable<<<256, 256, 0, stream>>>(emb, Wf, bf, Wi, bi, Wo, bo, Wg, bg, zx);
  k1_prep<<<1088, 256, 0, stream>>>(Wf, Wi, Wo, Wg, h0, Whh, hbuf);
  lstm_main<<<256, 256, 0, stream>>>(X, c0, zx, Whh, hbuf, flags, out);
}

// Round 2
// 1602.571 us; speedup vs baseline: 3.6310x; 3.6310x over previous
//
#include <hip/hip_runtime.h>

// LSTM: VOCAB=100, INPUT=512, HIDDEN=1024, BATCH=64, SEQ=512
// out = latent[64][512][1024] f32, then h_f[64][1024], c_f[64][1024]
// Dataflow design: latent itself is the h-exchange medium, sentinel-polled.

typedef _Float16 f16x8 __attribute__((ext_vector_type(8)));
typedef float    f32x4 __attribute__((ext_vector_type(4)));
typedef unsigned int u32x4 __attribute__((ext_vector_type(4)));

#define VOCABN 100
#define SENT 0x7F7F7F7Fu   // 3.396e38f; |h| < 1 strictly, can never alias

// ---------------- K0: zx_table[v][g*1024+n] = emb[v] . Wg[n,0:512] + b_g[n] ----------------
__global__ void k0_zxtable(const float* __restrict__ emb,
                           const float* __restrict__ Wf, const float* __restrict__ bf,
                           const float* __restrict__ Wi, const float* __restrict__ bi,
                           const float* __restrict__ Wo, const float* __restrict__ bo,
                           const float* __restrict__ Wg, const float* __restrict__ bg_,
                           float* __restrict__ zx) {
  const int bid = blockIdx.x;            // 256 blocks: (gate, 16-unit chunk)
  const int g = bid >> 6, chunk = bid & 63;
  const float* W = (g==0)?Wf:(g==1)?Wi:(g==2)?Wo:Wg;
  const float* B = (g==0)?bf:(g==1)?bi:(g==2)?bo:bg_;
  __shared__ float Wl[16][516];
  const int tid = threadIdx.x;
  for (int i = tid; i < 2048; i += 256) {
    int r = i >> 7, c4 = i & 127;
    float4 v = *(const float4*)&W[(size_t)(chunk*16 + r)*1536 + c4*4];
    Wl[r][c4*4+0]=v.x; Wl[r][c4*4+1]=v.y; Wl[r][c4*4+2]=v.z; Wl[r][c4*4+3]=v.w;
  }
  __syncthreads();
  const int u = tid & 15, vi = tid >> 4;
  for (int v0 = 0; v0 < VOCABN; v0 += 16) {
    int v = v0 + vi;
    if (v < VOCABN) {
      const float* er = emb + (size_t)v*512;
      float acc = 0.f;
      #pragma unroll 8
      for (int k = 0; k < 512; k++) acc += er[k]*Wl[u][k];
      zx[(size_t)v*4096 + g*1024 + chunk*16 + u] = acc + B[chunk*16 + u];
    }
  }
}

// ---------------- K1: Whh fp16 conversion ----------------
__global__ void k1_prep(const float* __restrict__ Wf, const float* __restrict__ Wi,
                        const float* __restrict__ Wo, const float* __restrict__ Wg,
                        _Float16* __restrict__ Whh) {
  const int bid = blockIdx.x, tid = threadIdx.x;
  #pragma unroll
  for (int i = 0; i < 4; i++) {
    int F = bid*1024 + i*256 + tid;            // float4 index, 2^20 total
    int g = F >> 18;
    int rem = F & ((1<<18)-1);
    int n = rem >> 8, k4 = rem & 255;
    const float* W = (g==0)?Wf:(g==1)?Wi:(g==2)?Wo:Wg;
    float4 v = *(const float4*)&W[(size_t)n*1536 + 512 + k4*4];
    _Float16 h4[4] = {(_Float16)v.x,(_Float16)v.y,(_Float16)v.z,(_Float16)v.w};
    *(unsigned long long*)&Whh[((size_t)g<<20) + (n<<10) + (k4<<2)] =
        *(unsigned long long*)h4;
  }
}

// ---------------- Main persistent LSTM: 256 blocks = 8 bg x 32 js, 512 thr ----------------
__global__ __launch_bounds__(512, 2) void lstm_main(
    const int* __restrict__ X, const float* __restrict__ h0,
    const float* __restrict__ c0, const float* __restrict__ zx,
    const _Float16* __restrict__ Whh, float* out)
{
  const int bid = blockIdx.x;
  const int bg  = bid >> 5;            // batch group: 8 batches
  const int js  = bid & 31;            // unit slice: 32 units (x4 gates = 128 cols)
  const int tid = threadIdx.x;
  const int w   = tid >> 6;            // wave 0..7: gate = w>>1, half = w&1
  const int lane = tid & 63;
  const int lm = lane & 15, lh = lane >> 4;

  __shared__ alignas(16) _Float16 hs[16][1032];   // rows 0..7 = batches; 8..15 garbage (discarded)
  __shared__ float zsh[8][132];                   // z exchange [batch][128 cols]

  // Preload weights: wave's 16 cols (units js*32 + (w&1)*16 + lm), K=1024 -> 128 VGPRs
  f16x8 bw[32];
  {
    const _Float16* wp = Whh + ((size_t)(w>>1)<<20)
                       + ((size_t)(js*32 + (w&1)*16 + lm)<<10) + (lh<<3);
    #pragma unroll
    for (int kk = 0; kk < 32; kk++) bw[kk] = *(const f16x8*)(wp + kk*32);
  }

  // staging role: row sr (batch), 16 floats at cols sc*4 + j*256
  const int sr = tid >> 6, sc = tid & 63;
  const float* h0p = h0 + (size_t)(bg*8 + sr)*1024 + sc*4;
  float* lat = out;                               // latent[64][512][1024]

  // gate-phase role (tid<256): one (batch b, unit u)
  const int b = (tid >> 5) & 7, u = tid & 31;
  const int brow = bg*8 + b, ucol = js*32 + u;
  float c = 0.f;
  const int* Xr = nullptr;
  if (tid < 256) {
    c = c0[(size_t)brow*1024 + ucol];
    Xr = X + (size_t)brow*512;
  }

  for (int t = 0; t < 512; t++) {
    // ---- prefetch token contribution (independent of h) ----
    float zx0=0.f, zx1=0.f, zx2=0.f, zx3=0.f;
    if (tid < 256) {
      int xv = Xr[t];
      const float* p = zx + (size_t)xv*4096 + ucol;
      zx0 = p[0]; zx1 = p[1024]; zx2 = p[2048]; zx3 = p[3072];
    }

    // ---- stage h_{t-1}: coherent loads + sentinel poll ----
    {
      const float* src = t ? (lat + ((size_t)(bg*8+sr)*512 + (t-1))*1024 + sc*4) : h0p;
      u32x4 v0, v1, v2, v3;
      for (;;) {
        asm volatile(
          "global_load_dwordx4 %0, %4, off sc1\n\t"
          "global_load_dwordx4 %1, %4, off offset:1024 sc1\n\t"
          "global_load_dwordx4 %2, %4, off offset:2048 sc1\n\t"
          "global_load_dwordx4 %3, %4, off offset:3072 sc1\n\t"
          "s_waitcnt vmcnt(0)"
          : "=&v"(v0), "=&v"(v1), "=&v"(v2), "=&v"(v3)
          : "v"(src));
        if (t == 0) break;
        bool bad = (v0.x==SENT)|(v0.y==SENT)|(v0.z==SENT)|(v0.w==SENT)
                 | (v1.x==SENT)|(v1.y==SENT)|(v1.z==SENT)|(v1.w==SENT)
                 | (v2.x==SENT)|(v2.y==SENT)|(v2.z==SENT)|(v2.w==SENT)
                 | (v3.x==SENT)|(v3.y==SENT)|(v3.z==SENT)|(v3.w==SENT);
        if (!bad) break;
        __builtin_amdgcn_s_sleep(1);
      }
      _Float16* dst = &hs[sr][sc*4];
      #define CVT_STORE(vv, J) { \
        _Float16 h4[4]; \
        h4[0]=(_Float16)__uint_as_float(vv.x); h4[1]=(_Float16)__uint_as_float(vv.y); \
        h4[2]=(_Float16)__uint_as_float(vv.z); h4[3]=(_Float16)__uint_as_float(vv.w); \
        *(unsigned long long*)(dst + J*256) = *(unsigned long long*)h4; }
      CVT_STORE(v0, 0) CVT_STORE(v1, 1) CVT_STORE(v2, 2) CVT_STORE(v3, 3)
      #undef CVT_STORE
    }
    __syncthreads();

    // ---- MFMA: z[8b x 16cols] per wave, K=1024 ----
    f32x4 a0={0,0,0,0}, a1={0,0,0,0}, a2={0,0,0,0}, a3={0,0,0,0};
    const _Float16* hrow = &hs[lm][lh<<3];
    #pragma unroll
    for (int kk = 0; kk < 32; kk += 4) {
      f16x8 x0 = *(const f16x8*)(hrow + (kk+0)*32);
      f16x8 x1 = *(const f16x8*)(hrow + (kk+1)*32);
      f16x8 x2 = *(const f16x8*)(hrow + (kk+2)*32);
      f16x8 x3 = *(const f16x8*)(hrow + (kk+3)*32);
      a0 = __builtin_amdgcn_mfma_f32_16x16x32_f16(x0, bw[kk+0], a0, 0, 0, 0);
      a1 = __builtin_amdgcn_mfma_f32_16x16x32_f16(x1, bw[kk+1], a1, 0, 0, 0);
      a2 = __builtin_amdgcn_mfma_f32_16x16x32_f16(x2, bw[kk+2], a2, 0, 0, 0);
      a3 = __builtin_amdgcn_mfma_f32_16x16x32_f16(x3, bw[kk+3], a3, 0, 0, 0);
    }
    f32x4 z4 = (a0 + a1) + (a2 + a3);
    if (lh < 2) {                      // D rows 0..7 valid: row=lh*4+r, col=lm
      #pragma unroll
      for (int r4 = 0; r4 < 4; r4++) zsh[lh*4 + r4][w*16 + lm] = z4[r4];
    }
    __syncthreads();

    // ---- gates + state update + fire-and-forget h publish ----
    if (tid < 256) {
      float zf = zsh[b][u]      + zx0;
      float zi = zsh[b][32+u]   + zx1;
      float zo = zsh[b][64+u]   + zx2;
      float zg = zsh[b][96+u]   + zx3;
      float fg = 1.f/(1.f + expf(-zf));
      float ig = 1.f/(1.f + expf(-zi));
      float og = 1.f/(1.f + expf(-zo));
      float gg = tanhf(zg);
      c = fg*c + ig*gg;
      float h = og*tanhf(c);
      __hip_atomic_store(lat + ((size_t)brow*512 + t)*1024 + ucol, h,
                         __ATOMIC_RELAXED, __HIP_MEMORY_SCOPE_AGENT);
      if (t == 511) {
        out[33554432 + (brow<<10) + ucol] = h;   // h_f
        out[33619968 + (brow<<10) + ucol] = c;   // c_f
      }
    }
    __syncthreads();   // protect hs/zsh reuse next step
  }
}

extern "C" void kernel_launch(void* const* d_in, const int* in_sizes, int n_in,
                              void* d_out, int out_size, void* d_ws, size_t ws_size,
                              hipStream_t stream) {
  const int*   X   = (const int*)  d_in[0];
  const float* h0  = (const float*)d_in[1];
  const float* c0  = (const float*)d_in[2];
  const float* emb = (const float*)d_in[3];
  const float* Wf  = (const float*)d_in[4];  const float* bf = (const float*)d_in[5];
  const float* Wi  = (const float*)d_in[6];  const float* bi = (const float*)d_in[7];
  const float* Wo  = (const float*)d_in[8];  const float* bo = (const float*)d_in[9];
  const float* Wg  = (const float*)d_in[10]; const float* bg = (const float*)d_in[11];
  float* out = (float*)d_out;

  char* ws = (char*)d_ws;
  float*    zx  = (float*)   ws;                 // 100*4096*4   = 1,638,400 B
  _Float16* Whh = (_Float16*)(ws + 1638400);     // 4*1024*1024*2 = 8,388,608 B

  // sentinel-fill the latent region (exchange medium); kernel-boundary flush
  // makes it visible at agent scope before lstm_main's sc1 loads
  hipMemsetAsync(out, 0x7F, (size_t)64*512*1024*4, stream);
  k0_zxtable<<<256, 256, 0, stream>>>(emb, Wf, bf, Wi, bi, Wo, bo, Wg, bg, zx);
  k1_prep<<<1024, 256, 0, stream>>>(Wf, Wi, Wo, Wg, Whh);
  lstm_main<<<256, 512, 0, stream>>>(X, h0, c0, zx, Whh, out);
}

// Round 4
// 1579.618 us; speedup vs baseline: 3.6837x; 1.0145x over previous
//
#include <hip/hip_runtime.h>

// LSTM: VOCAB=100, INPUT=512, HIDDEN=1024, BATCH=64, SEQ=512
// out = latent[64][512][1024] f32, then h_f[64][1024], c_f[64][1024]
// v4: v3 + cross-XCD fix (h publish at AGENT scope / sc1, not workgroup-plain).

typedef _Float16 f16x8 __attribute__((ext_vector_type(8)));
typedef float    f32x4 __attribute__((ext_vector_type(4)));
typedef unsigned int u32x4 __attribute__((ext_vector_type(4)));

#define VOCABN 100

// ---------------- K0: zx_table[v][g*1024+n] = emb[v] . Wg[n,0:512] + b_g[n] ----------------
__global__ void k0_zxtable(const float* __restrict__ emb,
                           const float* __restrict__ Wf, const float* __restrict__ bf,
                           const float* __restrict__ Wi, const float* __restrict__ bi,
                           const float* __restrict__ Wo, const float* __restrict__ bo,
                           const float* __restrict__ Wg, const float* __restrict__ bg_,
                           float* __restrict__ zx) {
  const int bid = blockIdx.x;            // 256 blocks: (gate, 16-unit chunk)
  const int g = bid >> 6, chunk = bid & 63;
  const float* W = (g==0)?Wf:(g==1)?Wi:(g==2)?Wo:Wg;
  const float* B = (g==0)?bf:(g==1)?bi:(g==2)?bo:bg_;
  __shared__ float Wl[16][516];
  const int tid = threadIdx.x;
  for (int i = tid; i < 2048; i += 256) {
    int r = i >> 7, c4 = i & 127;
    float4 v = *(const float4*)&W[(size_t)(chunk*16 + r)*1536 + c4*4];
    Wl[r][c4*4+0]=v.x; Wl[r][c4*4+1]=v.y; Wl[r][c4*4+2]=v.z; Wl[r][c4*4+3]=v.w;
  }
  __syncthreads();
  const int u = tid & 15, vi = tid >> 4;
  for (int v0 = 0; v0 < VOCABN; v0 += 16) {
    int v = v0 + vi;
    if (v < VOCABN) {
      const float* er = emb + (size_t)v*512;
      float acc = 0.f;
      #pragma unroll 8
      for (int k = 0; k < 512; k++) acc += er[k]*Wl[u][k];
      zx[(size_t)v*4096 + g*1024 + chunk*16 + u] = acc + B[chunk*16 + u];
    }
  }
}

// ---------------- K1: Whh fp16 conversion ----------------
__global__ void k1_prep(const float* __restrict__ Wf, const float* __restrict__ Wi,
                        const float* __restrict__ Wo, const float* __restrict__ Wg,
                        _Float16* __restrict__ Whh) {
  const int bid = blockIdx.x, tid = threadIdx.x;
  #pragma unroll
  for (int i = 0; i < 4; i++) {
    int F = bid*1024 + i*256 + tid;            // float4 index, 2^20 total
    int g = F >> 18;
    int rem = F & ((1<<18)-1);
    int n = rem >> 8, k4 = rem & 255;
    const float* W = (g==0)?Wf:(g==1)?Wi:(g==2)?Wo:Wg;
    float4 v = *(const float4*)&W[(size_t)n*1536 + 512 + k4*4];
    _Float16 h4[4] = {(_Float16)v.x,(_Float16)v.y,(_Float16)v.z,(_Float16)v.w};
    *(unsigned long long*)&Whh[((size_t)g<<20) + (n<<10) + (k4<<2)] =
        *(unsigned long long*)h4;
  }
}

// ---------------- Main persistent LSTM: 256 blocks = 8 bg x 32 js, 512 thr ----------------
__global__ __launch_bounds__(512, 2) void lstm_main(
    const int* __restrict__ X, const float* __restrict__ h0,
    const float* __restrict__ c0, const float* __restrict__ zx,
    const _Float16* __restrict__ Whh, _Float16* __restrict__ hx,
    int* __restrict__ flags, float* out)
{
  const int bid = blockIdx.x;
  const int bg  = bid >> 5;            // batch group: 8 batches
  const int js  = bid & 31;            // unit slice: 32 units (x4 gates = 128 cols)
  const int tid = threadIdx.x;
  const int w   = tid >> 6;            // wave 0..7: gate = w>>1, half = w&1
  const int lane = tid & 63;
  const int lm = lane & 15, lh = lane >> 4;

  __shared__ alignas(16) _Float16 hs[16*1024];    // rows: 2KB stride, XOR-swizzled
  __shared__ float zsh[8][132];                   // z exchange [batch][128 cols]

  // ---- weights: asm loads -> guaranteed VGPR residency (128 VGPRs) ----
  f16x8 bw[32];
  {
    const _Float16* wp = Whh + ((size_t)(w>>1)<<20)
                       + ((size_t)(js*32 + (w&1)*16 + lm)<<10) + (lh<<3);
    #pragma unroll
    for (int kk = 0; kk < 32; kk++) {
      asm volatile("global_load_dwordx4 %0, %1, off"
                   : "=&v"(bw[kk]) : "v"(wp + kk*32));
    }
    asm volatile("s_waitcnt vmcnt(0)");
    __builtin_amdgcn_sched_barrier(0);   // rule #18: no consumer hoists above waitcnt
  }

  // staging role: row sr (batch), cols sc*16..sc*16+15 (32B fp16)
  const int sr = tid >> 6, sc = tid & 63;
  const int fidx = (bg << 5) + (sc >> 1);         // the ONE producer this thread needs

  // gate-phase role (tid<256): one (batch b, unit u)
  const int b = (tid >> 5) & 7, u = tid & 31;
  const int brow = bg*8 + b, ucol = js*32 + u;
  float c = 0.f;
  const int* Xr = nullptr;
  if (tid < 256) {
    c = c0[(size_t)brow*1024 + ucol];
    Xr = X + (size_t)brow*512;
  }
  float* latp = out + (size_t)brow*512*1024 + ucol;

  char* hrow_w = (char*)hs + (sr << 11);          // staging write base
  const char* hrow_r = (const char*)hs + (lm << 11);  // MFMA read base
  const int sww = (sr & 7) << 4, swr = (lm & 7) << 4;

  for (int t = 0; t < 512; t++) {
    // ---- prefetch token contribution (independent of h) ----
    float zx0=0.f, zx1=0.f, zx2=0.f, zx3=0.f;
    if (tid < 256) {
      int xv = Xr[t];
      const float* p = zx + (size_t)xv*4096 + ucol;
      zx0 = p[0]; zx1 = p[1024]; zx2 = p[2048]; zx3 = p[3072];
    }

    // ---- stage h_{t-1} into LDS (swizzled) ----
    if (t == 0) {
      const float* s0 = h0 + ((size_t)(bg*8+sr)<<10) + (sc<<4);
      float4 f0 = *(const float4*)(s0+0),  f1 = *(const float4*)(s0+4);
      float4 f2 = *(const float4*)(s0+8),  f3 = *(const float4*)(s0+12);
      _Float16 hh[16] = {(_Float16)f0.x,(_Float16)f0.y,(_Float16)f0.z,(_Float16)f0.w,
                         (_Float16)f1.x,(_Float16)f1.y,(_Float16)f1.z,(_Float16)f1.w,
                         (_Float16)f2.x,(_Float16)f2.y,(_Float16)f2.z,(_Float16)f2.w,
                         (_Float16)f3.x,(_Float16)f3.y,(_Float16)f3.z,(_Float16)f3.w};
      int off = (sc << 5) ^ sww;
      *(u32x4*)(hrow_w + off)        = *(u32x4*)&hh[0];
      *(u32x4*)(hrow_w + (off ^ 16)) = *(u32x4*)&hh[8];
    } else {
      // poll my producer's flag (4B sc1 load, trivial BW)
      while (__hip_atomic_load(&flags[fidx], __ATOMIC_RELAXED,
                               __HIP_MEMORY_SCOPE_AGENT) < t) {}
      const _Float16* src = hx + (((t-1)&1)<<16) + ((size_t)(bg*8+sr)<<10) + (sc<<4);
      u32x4 va, vb;
      asm volatile(
        "global_load_dwordx4 %0, %2, off sc1\n\t"
        "global_load_dwordx4 %1, %2, off offset:16 sc1\n\t"
        "s_waitcnt vmcnt(0)"
        : "=&v"(va), "=&v"(vb) : "v"(src));
      int off = (sc << 5) ^ sww;
      *(u32x4*)(hrow_w + off)        = va;
      *(u32x4*)(hrow_w + (off ^ 16)) = vb;
    }
    __syncthreads();

    // ---- MFMA: z[8b x 16cols] per wave, K=1024, swizzled reads ----
    f32x4 a0={0,0,0,0}, a1={0,0,0,0}, a2={0,0,0,0}, a3={0,0,0,0};
    #pragma unroll
    for (int kk = 0; kk < 32; kk += 4) {
      f16x8 x0 = *(const f16x8*)(hrow_r + ((((kk+0)<<6) + (lh<<4)) ^ swr));
      f16x8 x1 = *(const f16x8*)(hrow_r + ((((kk+1)<<6) + (lh<<4)) ^ swr));
      f16x8 x2 = *(const f16x8*)(hrow_r + ((((kk+2)<<6) + (lh<<4)) ^ swr));
      f16x8 x3 = *(const f16x8*)(hrow_r + ((((kk+3)<<6) + (lh<<4)) ^ swr));
      a0 = __builtin_amdgcn_mfma_f32_16x16x32_f16(x0, bw[kk+0], a0, 0, 0, 0);
      a1 = __builtin_amdgcn_mfma_f32_16x16x32_f16(x1, bw[kk+1], a1, 0, 0, 0);
      a2 = __builtin_amdgcn_mfma_f32_16x16x32_f16(x2, bw[kk+2], a2, 0, 0, 0);
      a3 = __builtin_amdgcn_mfma_f32_16x16x32_f16(x3, bw[kk+3], a3, 0, 0, 0);
    }
    f32x4 z4 = (a0 + a1) + (a2 + a3);
    if (lh < 2) {                      // D rows 0..7 valid: row=lh*4+r, col=lm
      #pragma unroll
      for (int r4 = 0; r4 < 4; r4++) zsh[lh*4 + r4][w*16 + lm] = z4[r4];
    }
    __syncthreads();

    // ---- gates + state update ----
    float h = 0.f;
    if (tid < 256) {
      float zf = zsh[b][u]      + zx0;
      float zi = zsh[b][32+u]   + zx1;
      float zo = zsh[b][64+u]   + zx2;
      float zg = zsh[b][96+u]   + zx3;
      float fg = 1.f/(1.f + __expf(-zf));
      float ig = 1.f/(1.f + __expf(-zi));
      float og = 1.f/(1.f + __expf(-zo));
      float e2g = __expf(2.f*zg);
      float gg = 1.f - 2.f/(e2g + 1.f);
      c = fg*c + ig*gg;
      float e2c = __expf(2.f*c);
      h = og*(1.f - 2.f/(e2c + 1.f));
      if (t < 511) {
        // publish h as packed fp16 pair — AGENT scope => sc1 write-through to MALL
        _Float16 hf = (_Float16)h;
        unsigned short hu = __builtin_bit_cast(unsigned short, hf);
        unsigned pu = (unsigned)__shfl_xor((int)hu, 1);
        if ((u & 1) == 0) {
          unsigned word = (unsigned)hu | (pu << 16);
          __hip_atomic_store((unsigned*)(hx + ((t&1)<<16) + ((size_t)brow<<10) + ucol),
                             word, __ATOMIC_RELAXED, __HIP_MEMORY_SCOPE_AGENT);
        }
      }
    }
    __syncthreads();   // vmcnt(0) drain: sc1 stores ack'd at MALL; hs/zsh reuse safe
    if (tid == 0 && t < 511)
      __hip_atomic_store(&flags[bid], t+1, __ATOMIC_RELAXED, __HIP_MEMORY_SCOPE_AGENT);
    // latent f32 output: nontemporal, off the critical path
    if (tid < 256) {
      __builtin_nontemporal_store(h, latp + (size_t)t*1024);
      if (t == 511) {
        out[33554432 + ((size_t)brow<<10) + ucol] = h;   // h_f
        out[33619968 + ((size_t)brow<<10) + ucol] = c;   // c_f
      }
    }
  }
}

extern "C" void kernel_launch(void* const* d_in, const int* in_sizes, int n_in,
                              void* d_out, int out_size, void* d_ws, size_t ws_size,
                              hipStream_t stream) {
  const int*   X   = (const int*)  d_in[0];
  const float* h0  = (const float*)d_in[1];
  const float* c0  = (const float*)d_in[2];
  const float* emb = (const float*)d_in[3];
  const float* Wf  = (const float*)d_in[4];  const float* bf = (const float*)d_in[5];
  const float* Wi  = (const float*)d_in[6];  const float* bi = (const float*)d_in[7];
  const float* Wo  = (const float*)d_in[8];  const float* bo = (const float*)d_in[9];
  const float* Wg  = (const float*)d_in[10]; const float* bg = (const float*)d_in[11];
  float* out = (float*)d_out;

  char* ws = (char*)d_ws;
  float*    zx    = (float*)   ws;                          // 1,638,400 B
  _Float16* Whh   = (_Float16*)(ws + 1638400);              // 8,388,608 B
  _Float16* hx    = (_Float16*)(ws + 1638400 + 8388608);    // 2*64*1024*2 = 262,144 B
  int*      flags = (int*)     (ws + 1638400 + 8388608 + 262144);  // 1024 B

  hipMemsetAsync(flags, 0, 256*sizeof(int), stream);
  k0_zxtable<<<256, 256, 0, stream>>>(emb, Wf, bf, Wi, bi, Wo, bo, Wg, bg, zx);
  k1_prep<<<1024, 256, 0, stream>>>(Wf, Wi, Wo, Wg, Whh);
  lstm_main<<<256, 512, 0, stream>>>(X, h0, c0, zx, Whh, hx, flags, out);
}